// Round 1
// baseline (887.134 us; speedup 1.0000x reference)
//
#include <hip/hip_runtime.h>
#include <hip/hip_bf16.h>

// ---------------------------------------------------------------------------
// InterpretableMultiHeadAttention on MI355X (gfx950)
// B=4, S=2048, D=1024, H=16, Dh=64
// Pipeline:
//   K1 x3 : Q/K/V projections, split-bf16 (hi/lo) MFMA GEMM, f32 accum
//           Q,K stored [B,H,S,Dh] hi/lo ; V stored transposed [B,H,Dh,S] bf16
//   K2    : flash attention per (b,h,qtile64): scores via split QK^T (exact to
//           ~2^-18), online softmax f32, PV in plain bf16; writes attn_out f32
//           and per-row m,l for K3.
//   K3    : avg_attention per (b,qtile64,ktile64): loops all 16 heads,
//           recomputes scores (bitwise-identical MFMA sequence), accumulates
//           mean prob in registers, one coalesced write. No atomics.
//   K4    : out = attn_out @ Wo^T + bo, split-bf16 GEMM, f32 out.
// ---------------------------------------------------------------------------

#define DEVI __device__ __forceinline__

typedef __attribute__((ext_vector_type(8))) short bf16x8;
typedef __attribute__((ext_vector_type(4))) short bf16x4;
typedef __attribute__((ext_vector_type(4))) float f32x4;

#define MFMA_BF16(a, b, c) __builtin_amdgcn_mfma_f32_16x16x32_bf16(a, b, c, 0, 0, 0)

constexpr int Bn = 4;
constexpr int Sn = 2048;
constexpr int Dn = 1024;
constexpr int Hn = 16;

// round-to-nearest-even f32 -> bf16 (bit pattern)
DEVI unsigned short f2bf_rn(float x) {
    unsigned u = __float_as_uint(x);
    u += 0x7fffu + ((u >> 16) & 1u);
    return (unsigned short)(u >> 16);
}
DEVI float bf2f(unsigned short h) { return __uint_as_float(((unsigned)h) << 16); }

// XOR swizzles: element index within a row-major bf16 tile, conflict-free for
// both b128 staging writes and fragment reads.
DEVI int swz32(int r, int k) { return r * 32 + ((((k >> 3) ^ r) & 3) << 3) + (k & 7); }
DEVI int swz64(int r, int k) { return r * 64 + ((((k >> 3) ^ r) & 7) << 3) + (k & 7); }

// ---------------------------------------------------------------------------
// Split-bf16 GEMM:  C[row,col] = sum_k X[row,k] * W[col,k] + bias[col]
// M=8192, N=1024, K=1024.  MODE 0: write hi/lo bf16 at [B,H,S,Dh] (Q,K)
//                          MODE 1: write bf16 at [B,H,Dh,S]       (V^T)
//                          MODE 2: write f32 row-major [M,N]      (final out)
// ---------------------------------------------------------------------------
template <int MODE>
__global__ __launch_bounds__(256) void gemm_xwt(
    const float* __restrict__ X, const float* __restrict__ W,
    const float* __restrict__ bias,
    unsigned short* __restrict__ o_hi, unsigned short* __restrict__ o_lo,
    float* __restrict__ o_f32)
{
    constexpr int K = Dn;
    __shared__ __align__(16) unsigned short sAhi[128 * 32];
    __shared__ __align__(16) unsigned short sAlo[128 * 32];
    __shared__ __align__(16) unsigned short sBhi[128 * 32];
    __shared__ __align__(16) unsigned short sBlo[128 * 32];

    const int tid = threadIdx.x, lane = tid & 63, w = tid >> 6;
    const int row0 = blockIdx.y * 128, col0 = blockIdx.x * 128;
    const int wm = (w >> 1) * 64, wn = (w & 1) * 64;
    const int fr = lane & 15, kof = (lane >> 4) * 8;

    f32x4 acc[4][4] = {};

    for (int k0 = 0; k0 < K; k0 += 32) {
#pragma unroll
        for (int j = 0; j < 4; ++j) {
            const int u = tid + j * 256;
            const int r = u >> 3, c4 = (u & 7) * 4;
            const float4 va = *reinterpret_cast<const float4*>(X + (size_t)(row0 + r) * K + k0 + c4);
            const float4 vb = *reinterpret_cast<const float4*>(W + (size_t)(col0 + r) * K + k0 + c4);
            bf16x4 ah, al, bh, bl;
            const float* pa = reinterpret_cast<const float*>(&va);
            const float* pb = reinterpret_cast<const float*>(&vb);
#pragma unroll
            for (int i = 0; i < 4; ++i) {
                unsigned short h = f2bf_rn(pa[i]);
                ah[i] = (short)h;
                al[i] = (short)f2bf_rn(pa[i] - bf2f(h));
                h = f2bf_rn(pb[i]);
                bh[i] = (short)h;
                bl[i] = (short)f2bf_rn(pb[i] - bf2f(h));
            }
            const int ia = swz32(r, c4);
            *(bf16x4*)&sAhi[ia] = ah;
            *(bf16x4*)&sAlo[ia] = al;
            *(bf16x4*)&sBhi[ia] = bh;
            *(bf16x4*)&sBlo[ia] = bl;
        }
        __syncthreads();

        bf16x8 fah[4], fal[4], fbh[4], fbl[4];
#pragma unroll
        for (int m = 0; m < 4; ++m) {
            const int ia = swz32(wm + m * 16 + fr, kof);
            fah[m] = *(const bf16x8*)&sAhi[ia];
            fal[m] = *(const bf16x8*)&sAlo[ia];
        }
#pragma unroll
        for (int n = 0; n < 4; ++n) {
            const int ib = swz32(wn + n * 16 + fr, kof);
            fbh[n] = *(const bf16x8*)&sBhi[ib];
            fbl[n] = *(const bf16x8*)&sBlo[ib];
        }
#pragma unroll
        for (int m = 0; m < 4; ++m)
#pragma unroll
            for (int n = 0; n < 4; ++n) {
                acc[m][n] = MFMA_BF16(fah[m], fbh[n], acc[m][n]);
                acc[m][n] = MFMA_BF16(fah[m], fbl[n], acc[m][n]);
                acc[m][n] = MFMA_BF16(fal[m], fbh[n], acc[m][n]);
            }
        __syncthreads();
    }

    float bv_[4];
#pragma unroll
    for (int n = 0; n < 4; ++n) bv_[n] = bias[col0 + wn + n * 16 + fr];

#pragma unroll
    for (int m = 0; m < 4; ++m)
#pragma unroll
        for (int n = 0; n < 4; ++n)
#pragma unroll
            for (int r = 0; r < 4; ++r) {
                const int row = row0 + wm + m * 16 + (lane >> 4) * 4 + r;
                const int col = col0 + wn + n * 16 + fr;
                const float v = acc[m][n][r] + bv_[n];
                if (MODE == 0) {
                    const int bb = row >> 11, s = row & 2047;
                    const int hh = col >> 6, dh = col & 63;
                    const size_t idx = ((size_t)(bb * Hn + hh) * Sn + s) * 64 + dh;
                    const unsigned short hi = f2bf_rn(v);
                    o_hi[idx] = hi;
                    o_lo[idx] = f2bf_rn(v - bf2f(hi));
                } else if (MODE == 1) {
                    const int bb = row >> 11, s = row & 2047;
                    const int hh = col >> 6, dh = col & 63;
                    const size_t idx = ((size_t)(bb * Hn + hh) * 64 + dh) * Sn + s;
                    o_hi[idx] = f2bf_rn(v);
                } else {
                    o_f32[(size_t)row * Dn + col] = v;
                }
            }
}

// ---------------------------------------------------------------------------
// K2: flash attention.  One block = (b, h, qtile of 64 rows), 4 waves x 16 rows.
// ---------------------------------------------------------------------------
__global__ __launch_bounds__(256) void flash_fwd(
    const unsigned short* __restrict__ Qhi, const unsigned short* __restrict__ Qlo,
    const unsigned short* __restrict__ Khi, const unsigned short* __restrict__ Klo,
    const unsigned short* __restrict__ Vt,
    float* __restrict__ attn_out, float* __restrict__ m_ws, float* __restrict__ l_ws)
{
    __shared__ __align__(16) unsigned short kh_l[64 * 64];
    __shared__ __align__(16) unsigned short kl_l[64 * 64];
    __shared__ __align__(16) unsigned short vt_l[64 * 64];
    __shared__ __align__(16) unsigned short p_l[4 * 16 * 64];

    const int tid = threadIdx.x, lane = tid & 63, w = tid >> 6;
    const int qt = blockIdx.x & 31;
    const int h = (blockIdx.x >> 5) & 15;
    const int b = blockIdx.x >> 9;
    const int fr = lane & 15, kof = (lane >> 4) * 8;
    const size_t head = (size_t)(b * Hn + h) * Sn;
    const int qbase = qt * 64;
    const int qrow = qbase + w * 16 + fr;

    bf16x8 aqh[2], aql[2];
    {
        const unsigned short* qp = Qhi + (head + qrow) * 64;
        const unsigned short* ql = Qlo + (head + qrow) * 64;
        aqh[0] = *(const bf16x8*)(qp + kof);
        aqh[1] = *(const bf16x8*)(qp + 32 + kof);
        aql[0] = *(const bf16x8*)(ql + kof);
        aql[1] = *(const bf16x8*)(ql + 32 + kof);
    }

    float m_r[4] = {-1e30f, -1e30f, -1e30f, -1e30f};
    float l_r[4] = {0.f, 0.f, 0.f, 0.f};
    f32x4 o[4] = {};

    for (int kb = 0; kb < Sn; kb += 64) {
#pragma unroll
        for (int j = 0; j < 2; ++j) {
            const int u = tid + j * 256;
            const int r = u >> 3, sg = (u & 7) * 8;
            *(bf16x8*)&kh_l[swz64(r, sg)] = *(const bf16x8*)(Khi + (head + kb + r) * 64 + sg);
            *(bf16x8*)&kl_l[swz64(r, sg)] = *(const bf16x8*)(Klo + (head + kb + r) * 64 + sg);
            *(bf16x8*)&vt_l[swz64(r, sg)] =
                *(const bf16x8*)(Vt + ((size_t)(b * Hn + h) * 64 + r) * Sn + kb + sg);
        }
        __syncthreads();

        f32x4 sc[4] = {};
#pragma unroll
        for (int n = 0; n < 4; ++n) {
            const int kr = n * 16 + fr;
#pragma unroll
            for (int ks = 0; ks < 2; ++ks) {
                const bf16x8 bh = *(const bf16x8*)&kh_l[swz64(kr, ks * 32 + kof)];
                const bf16x8 bl = *(const bf16x8*)&kl_l[swz64(kr, ks * 32 + kof)];
                sc[n] = MFMA_BF16(aqh[ks], bh, sc[n]);
                sc[n] = MFMA_BF16(aqh[ks], bl, sc[n]);
                sc[n] = MFMA_BF16(aql[ks], bh, sc[n]);
            }
        }
#pragma unroll
        for (int n = 0; n < 4; ++n) sc[n] *= 0.125f;

        float mnew[4], scale_[4], rsum[4];
#pragma unroll
        for (int r = 0; r < 4; ++r) {
            float rm = fmaxf(fmaxf(sc[0][r], sc[1][r]), fmaxf(sc[2][r], sc[3][r]));
            rm = fmaxf(rm, __shfl_xor(rm, 1));
            rm = fmaxf(rm, __shfl_xor(rm, 2));
            rm = fmaxf(rm, __shfl_xor(rm, 4));
            rm = fmaxf(rm, __shfl_xor(rm, 8));
            mnew[r] = fmaxf(m_r[r], rm);
            scale_[r] = __expf(m_r[r] - mnew[r]);
            rsum[r] = 0.f;
        }
#pragma unroll
        for (int n = 0; n < 4; ++n)
#pragma unroll
            for (int r = 0; r < 4; ++r) {
                o[n][r] *= scale_[r];
                const float p = __expf(sc[n][r] - mnew[r]);
                rsum[r] += p;
                p_l[w * 1024 + swz64((lane >> 4) * 4 + r, n * 16 + fr)] = f2bf_rn(p);
            }
#pragma unroll
        for (int r = 0; r < 4; ++r) {
            float t = rsum[r];
            t += __shfl_xor(t, 1);
            t += __shfl_xor(t, 2);
            t += __shfl_xor(t, 4);
            t += __shfl_xor(t, 8);
            l_r[r] = l_r[r] * scale_[r] + t;
            m_r[r] = mnew[r];
        }

        const bf16x8 pa0 = *(const bf16x8*)&p_l[w * 1024 + swz64(fr, kof)];
        const bf16x8 pa1 = *(const bf16x8*)&p_l[w * 1024 + swz64(fr, 32 + kof)];
#pragma unroll
        for (int n = 0; n < 4; ++n) {
            const bf16x8 bv0 = *(const bf16x8*)&vt_l[swz64(n * 16 + fr, kof)];
            const bf16x8 bv1 = *(const bf16x8*)&vt_l[swz64(n * 16 + fr, 32 + kof)];
            o[n] = MFMA_BF16(pa0, bv0, o[n]);
            o[n] = MFMA_BF16(pa1, bv1, o[n]);
        }
        __syncthreads();
    }

#pragma unroll
    for (int r = 0; r < 4; ++r) {
        const float inv = 1.f / l_r[r];
        const int row_ = qbase + w * 16 + (lane >> 4) * 4 + r;
#pragma unroll
        for (int n = 0; n < 4; ++n)
            attn_out[((size_t)(b * Sn + row_)) * Dn + h * 64 + n * 16 + fr] = o[n][r] * inv;
    }
    if (fr == 0) {
#pragma unroll
        for (int r = 0; r < 4; ++r) {
            const int row_ = qbase + w * 16 + (lane >> 4) * 4 + r;
            m_ws[head + row_] = m_r[r];
            l_ws[head + row_] = l_r[r];
        }
    }
}

// ---------------------------------------------------------------------------
// K3: avg_attention.  One block = (b, qtile64, ktile64); loops all 16 heads,
// recomputes scores with the identical MFMA sequence as K2, uses (m,l).
// ---------------------------------------------------------------------------
__global__ __launch_bounds__(256) void avg_attn_kernel(
    const unsigned short* __restrict__ Qhi, const unsigned short* __restrict__ Qlo,
    const unsigned short* __restrict__ Khi, const unsigned short* __restrict__ Klo,
    const float* __restrict__ m_ws, const float* __restrict__ l_ws,
    float* __restrict__ avg)
{
    __shared__ __align__(16) unsigned short kh_l[64 * 64];
    __shared__ __align__(16) unsigned short kl_l[64 * 64];

    const int tid = threadIdx.x, lane = tid & 63, w = tid >> 6;
    const int kt = blockIdx.x & 31;
    const int qt = (blockIdx.x >> 5) & 31;
    const int b = blockIdx.x >> 10;
    const int fr = lane & 15, kof = (lane >> 4) * 8;
    const int qbase = qt * 64, kbase = kt * 64;
    const int qrow = qbase + w * 16 + fr;

    f32x4 facc[4] = {};

    for (int h = 0; h < Hn; ++h) {
        const size_t head = (size_t)(b * Hn + h) * Sn;
#pragma unroll
        for (int j = 0; j < 2; ++j) {
            const int u = tid + j * 256;
            const int r = u >> 3, sg = (u & 7) * 8;
            *(bf16x8*)&kh_l[swz64(r, sg)] = *(const bf16x8*)(Khi + (head + kbase + r) * 64 + sg);
            *(bf16x8*)&kl_l[swz64(r, sg)] = *(const bf16x8*)(Klo + (head + kbase + r) * 64 + sg);
        }
        __syncthreads();

        const unsigned short* qp = Qhi + (head + qrow) * 64;
        const unsigned short* ql = Qlo + (head + qrow) * 64;
        const bf16x8 aqh0 = *(const bf16x8*)(qp + kof);
        const bf16x8 aqh1 = *(const bf16x8*)(qp + 32 + kof);
        const bf16x8 aql0 = *(const bf16x8*)(ql + kof);
        const bf16x8 aql1 = *(const bf16x8*)(ql + 32 + kof);

        f32x4 sc[4] = {};
#pragma unroll
        for (int n = 0; n < 4; ++n) {
            const int kr = n * 16 + fr;
            const bf16x8 bh0 = *(const bf16x8*)&kh_l[swz64(kr, kof)];
            const bf16x8 bl0 = *(const bf16x8*)&kl_l[swz64(kr, kof)];
            const bf16x8 bh1 = *(const bf16x8*)&kh_l[swz64(kr, 32 + kof)];
            const bf16x8 bl1 = *(const bf16x8*)&kl_l[swz64(kr, 32 + kof)];
            sc[n] = MFMA_BF16(aqh0, bh0, sc[n]);
            sc[n] = MFMA_BF16(aqh0, bl0, sc[n]);
            sc[n] = MFMA_BF16(aql0, bh0, sc[n]);
            sc[n] = MFMA_BF16(aqh1, bh1, sc[n]);
            sc[n] = MFMA_BF16(aqh1, bl1, sc[n]);
            sc[n] = MFMA_BF16(aql1, bh1, sc[n]);
        }
#pragma unroll
        for (int r = 0; r < 4; ++r) {
            const int row_ = qbase + w * 16 + (lane >> 4) * 4 + r;
            const float mm = m_ws[head + row_];
            const float li = 0.0625f / l_ws[head + row_];
#pragma unroll
            for (int n = 0; n < 4; ++n) {
                const float ss = sc[n][r] * 0.125f;
                facc[n][r] += __expf(ss - mm) * li;
            }
        }
        __syncthreads();
    }

#pragma unroll
    for (int r = 0; r < 4; ++r) {
        const int row_ = qbase + w * 16 + (lane >> 4) * 4 + r;
#pragma unroll
        for (int n = 0; n < 4; ++n)
            avg[((size_t)(b * Sn + row_)) * Sn + kbase + n * 16 + fr] = facc[n][r];
    }
}

// ---------------------------------------------------------------------------
extern "C" void kernel_launch(void* const* d_in, const int* in_sizes, int n_in,
                              void* d_out, int out_size, void* d_ws, size_t ws_size,
                              hipStream_t stream)
{
    const float* query = (const float*)d_in[0];
    const float* key_ = (const float*)d_in[1];
    const float* value = (const float*)d_in[2];
    const float* Wq = (const float*)d_in[3];
    const float* bq = (const float*)d_in[4];
    const float* Wk = (const float*)d_in[5];
    const float* bk = (const float*)d_in[6];
    const float* Wv = (const float*)d_in[7];
    const float* bv = (const float*)d_in[8];
    const float* Wo = (const float*)d_in[9];
    const float* bo = (const float*)d_in[10];

    const size_t QE = (size_t)Bn * Hn * Sn * 64;  // 8388608 elems
    unsigned short* Qhi = (unsigned short*)d_ws;
    unsigned short* Qlo = Qhi + QE;
    unsigned short* Khi = Qlo + QE;
    unsigned short* Klo = Khi + QE;
    unsigned short* Vt = Klo + QE;
    float* m_ws = (float*)(Vt + QE);
    float* l_ws = m_ws + (size_t)Bn * Hn * Sn;
    float* attn_out = l_ws + (size_t)Bn * Hn * Sn;

    float* out0 = (float*)d_out;
    float* avg = out0 + (size_t)Bn * Sn * Dn;

    const dim3 gg(8, 64), bb(256);
    gemm_xwt<0><<<gg, bb, 0, stream>>>(query, Wq, bq, Qhi, Qlo, nullptr);
    gemm_xwt<0><<<gg, bb, 0, stream>>>(key_, Wk, bk, Khi, Klo, nullptr);
    gemm_xwt<1><<<gg, bb, 0, stream>>>(value, Wv, bv, Vt, nullptr, nullptr);
    flash_fwd<<<dim3(Bn * Hn * (Sn / 64)), bb, 0, stream>>>(Qhi, Qlo, Khi, Klo, Vt,
                                                            attn_out, m_ws, l_ws);
    avg_attn_kernel<<<dim3(Bn * 32 * 32), bb, 0, stream>>>(Qhi, Qlo, Khi, Klo,
                                                           m_ws, l_ws, avg);
    gemm_xwt<2><<<gg, bb, 0, stream>>>(attn_out, Wo, bo, nullptr, nullptr, out0);
}

// Round 2
// 687.310 us; speedup vs baseline: 1.2907x; 1.2907x over previous
//
#include <hip/hip_runtime.h>
#include <hip/hip_bf16.h>

// ---------------------------------------------------------------------------
// InterpretableMultiHeadAttention on MI355X (gfx950)
// B=4, S=2048, D=1024, H=16, Dh=64
//
// Precision plan (error budget vs 4.3e-3 threshold):
//   - X-side operands: plain bf16 (pre-converted once)
//   - W-side operands: hi/lo split bf16 (pre-converted once) -> 2 MFMAs/tile
//   - QK^T: plain bf16 (score err ~2e-3 -> P rel err ~0.2%)
//   - PV: plain bf16 ; attn_out stored plain bf16 ; Wo GEMM split-W
// Pipeline:
//   P0: cvt_plain3  (query,key,value -> bf16)
//   P1: cvt_split4  (Wq,Wk,Wv,Wo -> hi/lo bf16)
//   K1 x3: gemm_bf<0/0/1>  Q,K -> [B,H,S,64] bf16 ; V -> [B,H,64,S] bf16
//   K2: flash_fwd  (online softmax, writes attn bf16 + per-row m,l)
//   K3: avg_attn   (recomputes scores bitwise-identically, uses m,l)
//   K4: gemm_bf<2> (attn @ Wo^T + bo -> f32 out)
// ---------------------------------------------------------------------------

#define DEVI __device__ __forceinline__

typedef __attribute__((ext_vector_type(8))) short bf16x8;
typedef __attribute__((ext_vector_type(4))) short bf16x4;
typedef __attribute__((ext_vector_type(4))) float f32x4;

#define MFMA_BF16(a, b, c) __builtin_amdgcn_mfma_f32_16x16x32_bf16(a, b, c, 0, 0, 0)

constexpr int Bn = 4;
constexpr int Sn = 2048;
constexpr int Dn = 1024;
constexpr int Hn = 16;

DEVI unsigned short f2bf_rn(float x) {
    unsigned u = __float_as_uint(x);
    u += 0x7fffu + ((u >> 16) & 1u);
    return (unsigned short)(u >> 16);
}
DEVI float bf2f(unsigned short h) { return __uint_as_float(((unsigned)h) << 16); }

// XOR swizzles (8-elem granules) — measured 0 bank conflicts in round 1.
DEVI int swz32(int r, int k) { return r * 32 + ((((k >> 3) ^ r) & 3) << 3) + (k & 7); }
DEVI int swz64(int r, int k) { return r * 64 + ((((k >> 3) ^ r) & 7) << 3) + (k & 7); }

// ---------------------------------------------------------------------------
// P0: plain f32 -> bf16 conversion for query/key/value (8.39M elems each)
// ---------------------------------------------------------------------------
__global__ __launch_bounds__(256) void cvt_plain3(
    const float* __restrict__ a, const float* __restrict__ b, const float* __restrict__ c,
    unsigned short* __restrict__ oa, unsigned short* __restrict__ ob,
    unsigned short* __restrict__ oc)
{
    const float* s = blockIdx.y == 0 ? a : blockIdx.y == 1 ? b : c;
    unsigned short* d = blockIdx.y == 0 ? oa : blockIdx.y == 1 ? ob : oc;
    const size_t i = ((size_t)blockIdx.x * 256 + threadIdx.x) * 8;
    const float4 v0 = *reinterpret_cast<const float4*>(s + i);
    const float4 v1 = *reinterpret_cast<const float4*>(s + i + 4);
    const float* p0 = reinterpret_cast<const float*>(&v0);
    const float* p1 = reinterpret_cast<const float*>(&v1);
    bf16x8 o;
#pragma unroll
    for (int j = 0; j < 4; ++j) {
        o[j] = (short)f2bf_rn(p0[j]);
        o[4 + j] = (short)f2bf_rn(p1[j]);
    }
    *reinterpret_cast<bf16x8*>(d + i) = o;
}

// ---------------------------------------------------------------------------
// P1: split f32 -> (hi,lo) bf16 for the four weight matrices (1.05M each)
// ---------------------------------------------------------------------------
__global__ __launch_bounds__(256) void cvt_split4(
    const float* __restrict__ w0, const float* __restrict__ w1,
    const float* __restrict__ w2, const float* __restrict__ w3,
    unsigned short* __restrict__ h0, unsigned short* __restrict__ l0,
    unsigned short* __restrict__ h1, unsigned short* __restrict__ l1,
    unsigned short* __restrict__ h2, unsigned short* __restrict__ l2,
    unsigned short* __restrict__ h3, unsigned short* __restrict__ l3)
{
    const int y = blockIdx.y;
    const float* s = y == 0 ? w0 : y == 1 ? w1 : y == 2 ? w2 : w3;
    unsigned short* dh = y == 0 ? h0 : y == 1 ? h1 : y == 2 ? h2 : h3;
    unsigned short* dl = y == 0 ? l0 : y == 1 ? l1 : y == 2 ? l2 : l3;
    const size_t i = ((size_t)blockIdx.x * 256 + threadIdx.x) * 8;
    const float4 v0 = *reinterpret_cast<const float4*>(s + i);
    const float4 v1 = *reinterpret_cast<const float4*>(s + i + 4);
    const float* p0 = reinterpret_cast<const float*>(&v0);
    const float* p1 = reinterpret_cast<const float*>(&v1);
    bf16x8 oh, ol;
#pragma unroll
    for (int j = 0; j < 4; ++j) {
        unsigned short h = f2bf_rn(p0[j]);
        oh[j] = (short)h;
        ol[j] = (short)f2bf_rn(p0[j] - bf2f(h));
        h = f2bf_rn(p1[j]);
        oh[4 + j] = (short)h;
        ol[4 + j] = (short)f2bf_rn(p1[j] - bf2f(h));
    }
    *reinterpret_cast<bf16x8*>(dh + i) = oh;
    *reinterpret_cast<bf16x8*>(dl + i) = ol;
}

// ---------------------------------------------------------------------------
// GEMM: C[row,col] = sum_k Xbf[row,k] * (Whi+Wlo)[col,k] + bias[col]
// M=8192, N=1024, K=1024.  2 MFMAs per (m,n) tile per k-step.
// MODE 0: bf16 out at [B,H,S,64]   (Q, K)
// MODE 1: bf16 out at [B,H,64,S]   (V^T)
// MODE 2: f32 out row-major [M,N]  (final out)
// ---------------------------------------------------------------------------
template <int MODE>
__global__ __launch_bounds__(256) void gemm_bf(
    const unsigned short* __restrict__ Xbf,
    const unsigned short* __restrict__ Whi, const unsigned short* __restrict__ Wlo,
    const float* __restrict__ bias,
    unsigned short* __restrict__ o_bf, float* __restrict__ o_f32)
{
    constexpr int K = Dn;
    __shared__ __align__(16) unsigned short sA[128 * 32];
    __shared__ __align__(16) unsigned short sBh[128 * 32];
    __shared__ __align__(16) unsigned short sBl[128 * 32];

    const int tid = threadIdx.x, lane = tid & 63, w = tid >> 6;
    const int row0 = blockIdx.y * 128, col0 = blockIdx.x * 128;
    const int wm = (w >> 1) * 64, wn = (w & 1) * 64;
    const int fr = lane & 15, kof = (lane >> 4) * 8;

    f32x4 acc[4][4] = {};

    for (int k0 = 0; k0 < K; k0 += 32) {
#pragma unroll
        for (int j = 0; j < 2; ++j) {
            const int v = tid + j * 256;           // 512 units of 8 elems
            const int r = v >> 2, c8 = (v & 3) * 8;
            const int ia = swz32(r, c8);
            *(bf16x8*)&sA[ia] = *(const bf16x8*)(Xbf + (size_t)(row0 + r) * K + k0 + c8);
            *(bf16x8*)&sBh[ia] = *(const bf16x8*)(Whi + (size_t)(col0 + r) * K + k0 + c8);
            *(bf16x8*)&sBl[ia] = *(const bf16x8*)(Wlo + (size_t)(col0 + r) * K + k0 + c8);
        }
        __syncthreads();

        bf16x8 fa[4], fbh[4], fbl[4];
#pragma unroll
        for (int m = 0; m < 4; ++m) fa[m] = *(const bf16x8*)&sA[swz32(wm + m * 16 + fr, kof)];
#pragma unroll
        for (int n = 0; n < 4; ++n) {
            const int ib = swz32(wn + n * 16 + fr, kof);
            fbh[n] = *(const bf16x8*)&sBh[ib];
            fbl[n] = *(const bf16x8*)&sBl[ib];
        }
#pragma unroll
        for (int m = 0; m < 4; ++m)
#pragma unroll
            for (int n = 0; n < 4; ++n) {
                acc[m][n] = MFMA_BF16(fa[m], fbh[n], acc[m][n]);
                acc[m][n] = MFMA_BF16(fa[m], fbl[n], acc[m][n]);
            }
        __syncthreads();
    }

    float bv_[4];
#pragma unroll
    for (int n = 0; n < 4; ++n) bv_[n] = bias[col0 + wn + n * 16 + fr];

#pragma unroll
    for (int m = 0; m < 4; ++m)
#pragma unroll
        for (int n = 0; n < 4; ++n)
#pragma unroll
            for (int r = 0; r < 4; ++r) {
                const int row = row0 + wm + m * 16 + (lane >> 4) * 4 + r;
                const int col = col0 + wn + n * 16 + fr;
                const float v = acc[m][n][r] + bv_[n];
                if (MODE == 0) {
                    const int bb = row >> 11, s = row & 2047;
                    const int hh = col >> 6, dh = col & 63;
                    o_bf[((size_t)(bb * Hn + hh) * Sn + s) * 64 + dh] = f2bf_rn(v);
                } else if (MODE == 1) {
                    const int bb = row >> 11, s = row & 2047;
                    const int hh = col >> 6, dh = col & 63;
                    o_bf[((size_t)(bb * Hn + hh) * 64 + dh) * Sn + s] = f2bf_rn(v);
                } else {
                    o_f32[(size_t)row * Dn + col] = v;
                }
            }
}

// ---------------------------------------------------------------------------
// K2: flash attention.  One block = (b, h, qtile64), 4 waves x 16 q-rows.
// Plain bf16 QK^T (8 MFMA) + bf16 PV (8 MFMA).  Exact rescale-skip.
// ---------------------------------------------------------------------------
__global__ __launch_bounds__(256) void flash_fwd(
    const unsigned short* __restrict__ Qbf, const unsigned short* __restrict__ Kbf,
    const unsigned short* __restrict__ Vt,
    unsigned short* __restrict__ attn_bf, float* __restrict__ m_ws, float* __restrict__ l_ws)
{
    __shared__ __align__(16) unsigned short kh_l[64 * 64];
    __shared__ __align__(16) unsigned short vt_l[64 * 64];
    __shared__ __align__(16) unsigned short p_l[4 * 16 * 64];

    const int tid = threadIdx.x, lane = tid & 63, w = tid >> 6;
    const int qt = blockIdx.x & 31;
    const int h = (blockIdx.x >> 5) & 15;
    const int b = blockIdx.x >> 9;
    const int fr = lane & 15, kof = (lane >> 4) * 8;
    const size_t head = (size_t)(b * Hn + h) * Sn;
    const int qbase = qt * 64;
    const int qrow = qbase + w * 16 + fr;

    bf16x8 aq[2];
    {
        const unsigned short* qp = Qbf + (head + qrow) * 64;
        aq[0] = *(const bf16x8*)(qp + kof);
        aq[1] = *(const bf16x8*)(qp + 32 + kof);
    }

    float m_r[4] = {-1e30f, -1e30f, -1e30f, -1e30f};
    float l_r[4] = {0.f, 0.f, 0.f, 0.f};
    f32x4 o[4] = {};

    for (int kb = 0; kb < Sn; kb += 64) {
#pragma unroll
        for (int j = 0; j < 2; ++j) {
            const int u = tid + j * 256;
            const int r = u >> 3, sg = (u & 7) * 8;
            *(bf16x8*)&kh_l[swz64(r, sg)] = *(const bf16x8*)(Kbf + (head + kb + r) * 64 + sg);
            *(bf16x8*)&vt_l[swz64(r, sg)] =
                *(const bf16x8*)(Vt + ((size_t)(b * Hn + h) * 64 + r) * Sn + kb + sg);
        }
        __syncthreads();

        f32x4 sc[4] = {};
#pragma unroll
        for (int n = 0; n < 4; ++n) {
            const int kr = n * 16 + fr;
#pragma unroll
            for (int ks = 0; ks < 2; ++ks) {
                const bf16x8 bh = *(const bf16x8*)&kh_l[swz64(kr, ks * 32 + kof)];
                sc[n] = MFMA_BF16(aq[ks], bh, sc[n]);
            }
        }
#pragma unroll
        for (int n = 0; n < 4; ++n) sc[n] *= 0.125f;

        float mnew[4];
        bool grow = false;
#pragma unroll
        for (int r = 0; r < 4; ++r) {
            float rm = fmaxf(fmaxf(sc[0][r], sc[1][r]), fmaxf(sc[2][r], sc[3][r]));
            rm = fmaxf(rm, __shfl_xor(rm, 1));
            rm = fmaxf(rm, __shfl_xor(rm, 2));
            rm = fmaxf(rm, __shfl_xor(rm, 4));
            rm = fmaxf(rm, __shfl_xor(rm, 8));
            mnew[r] = fmaxf(m_r[r], rm);
            grow = grow || (mnew[r] > m_r[r]);
        }
        if (__any((int)grow)) {   // exact: skip only when no row's max grew
#pragma unroll
            for (int r = 0; r < 4; ++r) {
                const float scale_ = __expf(m_r[r] - mnew[r]);
#pragma unroll
                for (int n = 0; n < 4; ++n) o[n][r] *= scale_;
                l_r[r] *= scale_;
                m_r[r] = mnew[r];
            }
        }

        float rsum[4] = {0.f, 0.f, 0.f, 0.f};
#pragma unroll
        for (int n = 0; n < 4; ++n)
#pragma unroll
            for (int r = 0; r < 4; ++r) {
                const float p = __expf(sc[n][r] - m_r[r]);
                rsum[r] += p;
                p_l[w * 1024 + swz64((lane >> 4) * 4 + r, n * 16 + fr)] = f2bf_rn(p);
            }
#pragma unroll
        for (int r = 0; r < 4; ++r) {
            float t = rsum[r];
            t += __shfl_xor(t, 1);
            t += __shfl_xor(t, 2);
            t += __shfl_xor(t, 4);
            t += __shfl_xor(t, 8);
            l_r[r] += t;
        }

        const bf16x8 pa0 = *(const bf16x8*)&p_l[w * 1024 + swz64(fr, kof)];
        const bf16x8 pa1 = *(const bf16x8*)&p_l[w * 1024 + swz64(fr, 32 + kof)];
#pragma unroll
        for (int n = 0; n < 4; ++n) {
            const bf16x8 bv0 = *(const bf16x8*)&vt_l[swz64(n * 16 + fr, kof)];
            const bf16x8 bv1 = *(const bf16x8*)&vt_l[swz64(n * 16 + fr, 32 + kof)];
            o[n] = MFMA_BF16(pa0, bv0, o[n]);
            o[n] = MFMA_BF16(pa1, bv1, o[n]);
        }
        __syncthreads();
    }

#pragma unroll
    for (int r = 0; r < 4; ++r) {
        const float inv = 1.f / l_r[r];
        const int row_ = qbase + w * 16 + (lane >> 4) * 4 + r;
#pragma unroll
        for (int n = 0; n < 4; ++n)
            attn_bf[((size_t)(b * Sn + row_)) * Dn + h * 64 + n * 16 + fr] =
                f2bf_rn(o[n][r] * inv);
    }
    if (fr == 0) {
#pragma unroll
        for (int r = 0; r < 4; ++r) {
            const int row_ = qbase + w * 16 + (lane >> 4) * 4 + r;
            m_ws[head + row_] = m_r[r];
            l_ws[head + row_] = l_r[r];
        }
    }
}

// ---------------------------------------------------------------------------
// K3: avg_attention.  One block = (b, qtile64, ktile64); loops 16 heads,
// recomputes scores with the bitwise-identical MFMA sequence, uses (m,l).
// ---------------------------------------------------------------------------
__global__ __launch_bounds__(256) void avg_attn_kernel(
    const unsigned short* __restrict__ Qbf, const unsigned short* __restrict__ Kbf,
    const float* __restrict__ m_ws, const float* __restrict__ l_ws,
    float* __restrict__ avg)
{
    __shared__ __align__(16) unsigned short kh_l[64 * 64];

    const int tid = threadIdx.x, lane = tid & 63, w = tid >> 6;
    const int kt = blockIdx.x & 31;
    const int qt = (blockIdx.x >> 5) & 31;
    const int b = blockIdx.x >> 10;
    const int fr = lane & 15, kof = (lane >> 4) * 8;
    const int qbase = qt * 64, kbase = kt * 64;
    const int qrow = qbase + w * 16 + fr;

    f32x4 facc[4] = {};

    for (int h = 0; h < Hn; ++h) {
        const size_t head = (size_t)(b * Hn + h) * Sn;
#pragma unroll
        for (int j = 0; j < 2; ++j) {
            const int u = tid + j * 256;
            const int r = u >> 3, sg = (u & 7) * 8;
            *(bf16x8*)&kh_l[swz64(r, sg)] = *(const bf16x8*)(Kbf + (head + kbase + r) * 64 + sg);
        }
        __syncthreads();

        const unsigned short* qp = Qbf + (head + qrow) * 64;
        const bf16x8 aq0 = *(const bf16x8*)(qp + kof);
        const bf16x8 aq1 = *(const bf16x8*)(qp + 32 + kof);

        f32x4 sc[4] = {};
#pragma unroll
        for (int n = 0; n < 4; ++n) {
            const int kr = n * 16 + fr;
            const bf16x8 bh0 = *(const bf16x8*)&kh_l[swz64(kr, kof)];
            const bf16x8 bh1 = *(const bf16x8*)&kh_l[swz64(kr, 32 + kof)];
            sc[n] = MFMA_BF16(aq0, bh0, sc[n]);
            sc[n] = MFMA_BF16(aq1, bh1, sc[n]);
        }
#pragma unroll
        for (int r = 0; r < 4; ++r) {
            const int row_ = qbase + w * 16 + (lane >> 4) * 4 + r;
            const float mm = m_ws[head + row_];
            const float li = 0.0625f / l_ws[head + row_];
#pragma unroll
            for (int n = 0; n < 4; ++n) {
                const float ss = sc[n][r] * 0.125f;
                facc[n][r] += __expf(ss - mm) * li;
            }
        }
        __syncthreads();
    }

#pragma unroll
    for (int r = 0; r < 4; ++r) {
        const int row_ = qbase + w * 16 + (lane >> 4) * 4 + r;
#pragma unroll
        for (int n = 0; n < 4; ++n)
            avg[((size_t)(b * Sn + row_)) * Sn + kbase + n * 16 + fr] = facc[n][r];
    }
}

// ---------------------------------------------------------------------------
extern "C" void kernel_launch(void* const* d_in, const int* in_sizes, int n_in,
                              void* d_out, int out_size, void* d_ws, size_t ws_size,
                              hipStream_t stream)
{
    const float* query = (const float*)d_in[0];
    const float* key_ = (const float*)d_in[1];
    const float* value = (const float*)d_in[2];
    const float* Wq = (const float*)d_in[3];
    const float* bq = (const float*)d_in[4];
    const float* Wk = (const float*)d_in[5];
    const float* bk = (const float*)d_in[6];
    const float* Wv = (const float*)d_in[7];
    const float* bv = (const float*)d_in[8];
    const float* Wo = (const float*)d_in[9];
    const float* bo = (const float*)d_in[10];

    const size_t QE = (size_t)Bn * Hn * Sn * 64;  // 8,388,608
    const size_t WE = (size_t)Dn * Dn;            // 1,048,576

    unsigned short* Qbf = (unsigned short*)d_ws;
    unsigned short* Kbf = Qbf + QE;
    unsigned short* Vt = Kbf + QE;
    unsigned short* Xq = Vt + QE;      // aliased by attn_bf after use
    unsigned short* Xk = Xq + QE;
    unsigned short* Xv = Xk + QE;
    unsigned short* Wqh = Xv + QE;
    unsigned short* Wql = Wqh + WE;
    unsigned short* Wkh = Wql + WE;
    unsigned short* Wkl = Wkh + WE;
    unsigned short* Wvh = Wkl + WE;
    unsigned short* Wvl = Wvh + WE;
    unsigned short* Woh = Wvl + WE;
    unsigned short* Wol = Woh + WE;
    float* m_ws = (float*)(Wol + WE);
    float* l_ws = m_ws + (size_t)Bn * Hn * Sn;
    unsigned short* attn_bf = Xq;  // query-plane dead after gemm Q

    float* out0 = (float*)d_out;
    float* avg = out0 + (size_t)Bn * Sn * Dn;

    cvt_plain3<<<dim3(4096, 3), 256, 0, stream>>>(query, key_, value, Xq, Xk, Xv);
    cvt_split4<<<dim3(512, 4), 256, 0, stream>>>(Wq, Wk, Wv, Wo, Wqh, Wql, Wkh, Wkl,
                                                 Wvh, Wvl, Woh, Wol);

    const dim3 gg(8, 64), bb(256);
    gemm_bf<0><<<gg, bb, 0, stream>>>(Xq, Wqh, Wql, bq, Qbf, nullptr);
    gemm_bf<0><<<gg, bb, 0, stream>>>(Xk, Wkh, Wkl, bk, Kbf, nullptr);
    gemm_bf<1><<<gg, bb, 0, stream>>>(Xv, Wvh, Wvl, bv, Vt, nullptr);
    flash_fwd<<<dim3(Bn * Hn * (Sn / 64)), bb, 0, stream>>>(Qbf, Kbf, Vt, attn_bf,
                                                            m_ws, l_ws);
    avg_attn_kernel<<<dim3(Bn * 32 * 32), bb, 0, stream>>>(Qbf, Kbf, m_ws, l_ws, avg);
    gemm_bf<2><<<gg, bb, 0, stream>>>(attn_bf, Woh, Wol, bo, nullptr, out0);
}